// Round 19
// baseline (5266.405 us; speedup 1.0000x reference)
//
#include <hip/hip_runtime.h>
#include <hip/hip_bf16.h>
#include <stdint.h>

// Problem constants (fixed by the reference): T=512, B=64, IN=H=1024, L=2
#define TT 512
#define BB 64
#define HH 1024
#define BH 65536    // B*H elements
#define KD 2048     // IN+H == H+H

typedef __attribute__((ext_vector_type(8))) short short8;
typedef __attribute__((ext_vector_type(4))) float f32x4;

__device__ __forceinline__ unsigned short f2bf(float f) {
  union { float f; unsigned int u; } v; v.f = f;
  unsigned int r = v.u + 0x7fffu + ((v.u >> 16) & 1u);  // RNE
  return (unsigned short)(r >> 16);
}
__device__ __forceinline__ float bf2f(unsigned short u) {
  union { unsigned int u; float f; } v; v.u = ((unsigned int)u) << 16; return v.f;
}
__device__ __forceinline__ float fsig(float x)  { return 1.0f / (1.0f + __expf(-x)); }
__device__ __forceinline__ float ftanhf(float x){ return 1.0f - 2.0f / (__expf(2.0f * x) + 1.0f); }

// ---------------- x -> bf16 (row-major) ----------------
__global__ void cvt_x_kernel(const float* __restrict__ x, unsigned short* __restrict__ xbf) {
  const int n4 = (TT * BB * 1024) / 4;
  int stride = gridDim.x * blockDim.x;
  for (int i = blockIdx.x * blockDim.x + threadIdx.x; i < n4; i += stride) {
    float4 v = ((const float4*)x)[i];
    unsigned long long p = (unsigned long long)f2bf(v.x)
        | ((unsigned long long)f2bf(v.y) << 16)
        | ((unsigned long long)f2bf(v.z) << 32)
        | ((unsigned long long)f2bf(v.w) << 48);
    ((unsigned long long*)xbf)[i] = p;
  }
}

// ---------------- W [4096][2048] f32 -> bf16, LDS-image layout (TRANSPOSED-C perm) ----
// Ws[g][kk 0..63][nrow 0..31][hi 0..3][8 bf16]; nrow: nt=nrow>>4, q=nrow&3, jl=(nrow>>2)&3
//   -> W row = q*1024 + g*8 + nt*4 + jl ; kk<32: k=kk*32+hi*8 ; kk>=32: k=1024+(kk-32)*32+hi*8
__global__ void cvt_w_kernel(const float* __restrict__ W, unsigned short* __restrict__ Ws) {
  int idx = blockIdx.x * blockDim.x + threadIdx.x;   // < 1,048,576
  int hi = idx & 3;
  int nr = (idx >> 2) & 31;
  int kk = (idx >> 7) & 63;
  int g  = idx >> 13;
  int q  = nr & 3;
  int jl = (nr >> 2) & 3;
  int nt = nr >> 4;
  int grow = (q << 10) + (g << 3) + (nt << 2) + jl;
  int k = ((kk < 32) ? (kk << 5) : (1024 + ((kk - 32) << 5))) + (hi << 3);
  const float* src = W + (size_t)grow * KD + k;
  float4 v0 = ((const float4*)src)[0];
  float4 v1 = ((const float4*)src)[1];
  unsigned long long p0 = (unsigned long long)f2bf(v0.x)
      | ((unsigned long long)f2bf(v0.y) << 16)
      | ((unsigned long long)f2bf(v0.z) << 32)
      | ((unsigned long long)f2bf(v0.w) << 48);
  unsigned long long p1 = (unsigned long long)f2bf(v1.x)
      | ((unsigned long long)f2bf(v1.y) << 16)
      | ((unsigned long long)f2bf(v1.z) << 32)
      | ((unsigned long long)f2bf(v1.w) << 48);
  unsigned long long* dst = (unsigned long long*)(Ws + ((size_t)g << 16) + (kk << 10) + (nr << 5) + (hi << 3));
  dst[0] = p0;
  dst[1] = p1;
}

// ---------------- initial h -> hist slot 0 (BLOCKED layout [cb][m][8]) ----------------
__global__ void init_state_kernel(const float* __restrict__ h0in,
                                  unsigned short* h0s0, unsigned short* h1s0) {
  int i = blockIdx.x * blockDim.x + threadIdx.x;  // < BH
  int m = i >> 10, c = i & 1023;
  int dst = ((c >> 3) << 9) + (m << 3) + (c & 7);
  h0s0[dst] = f2bf(h0in[i]);
  h1s0[dst] = f2bf(h0in[BH + i]);
}

// ---------------- post-pass: blocked bf16 hist -> row-major fp32 out ----------------
__global__ void finalize_kernel(const unsigned short* __restrict__ h0hist,
                                const unsigned short* __restrict__ h1hist,
                                float* __restrict__ out) {
  const size_t NCH = (size_t)(TT + 2) * (BH / 8);
  size_t stride = (size_t)gridDim.x * blockDim.x;
  for (size_t i = (size_t)blockIdx.x * blockDim.x + threadIdx.x; i < NCH; i += stride) {
    int p  = (int)(i >> 13);     // BH/8 = 8192
    int ci = (int)(i & 8191);
    int cb = ci >> 6, m = ci & 63;
    const unsigned short* src;
    size_t dbase;
    if (p < TT)       { src = h1hist + (size_t)(p + 1) * BH; dbase = (size_t)p * BH; }
    else if (p == TT) { src = h0hist + (size_t)TT * BH;      dbase = (size_t)TT * BH; }
    else              { src = h1hist + (size_t)TT * BH;      dbase = (size_t)TT * BH + BH; }
    const unsigned short* sp = src + ((size_t)ci << 3);
    ushort4 v0 = ((const ushort4*)sp)[0];
    ushort4 v1 = ((const ushort4*)sp)[1];
    float* dp = out + dbase + (m << 10) + (cb << 3);
    *(float4*)(dp)     = make_float4(bf2f(v0.x), bf2f(v0.y), bf2f(v0.z), bf2f(v0.w));
    *(float4*)(dp + 4) = make_float4(bf2f(v1.x), bf2f(v1.y), bf2f(v1.z), bf2f(v1.w));
  }
}

#define GLD(p)    __hip_atomic_load((p),  __ATOMIC_RELAXED, __HIP_MEMORY_SCOPE_AGENT)
#define GST(p, v) __hip_atomic_store((p), (v), __ATOMIC_RELAXED, __HIP_MEMORY_SCOPE_AGENT)

// spin until the 8 sub-counters (256B apart) sum to 128
__device__ __forceinline__ void poll128(int* base) {
  for (;;) {
    int s = 0;
#pragma unroll
    for (int j = 0; j < 8; j++)
      s += GLD(base + (j << 6));
    if (s >= 128) return;
    __builtin_amdgcn_s_sleep(1);
  }
}

// ---------------- persistent 2-layer LSTM, v14: r18 + cross-step A prefetch ----------------
// 256 blocks x 512 threads, 1 block/CU. Blocks 0-127: layer0, 128-255: layer1.
// TRANSPOSED MFMA, lane-local epilogue, BLOCKED h hist (full-line stores).
// Waves 0-3 (A): at iter s, consume REGISTER-PREFETCHED operand (xa/xb, loaded
// during iter s-1) for partial[s+1]; then issue loads for step s+2 (L0: x[s+2],
// no gate; L1: h0hist[s+3], gated monotone cnt0[s+2] -> lag 3). HBM latency of
// the A operand gets an entire step to resolve.
// Waves 4-7 (B): unchanged tight recurrence (lane0 poll, rolling-8 blocked
// h loads, dual MFMA, lane-local epilogue, full-line sc1 stores).
// End-of-step barrier is DRAIN-FREE for A: B-waves s_waitcnt vmcnt(0) (own
// h-stores), all waves lgkmcnt(0) (pbuf), raw s_barrier; A's in-flight
// prefetch loads cross the barrier (consumed next iter via data dependence).
// Publisher = tid 256 (a B-wave) after the barrier -> cnt implies h visible.
__global__ __launch_bounds__(512, 2) void lstm_persist(
    const unsigned short* __restrict__ W0s, const unsigned short* __restrict__ W1s,
    const float* __restrict__ b0, const float* __restrict__ b1,
    const unsigned short* __restrict__ xbf,
    unsigned short* h0hist, unsigned short* h1hist,
    const float* __restrict__ c0in, float* out, int* cnt)
{
  __shared__ short8 wlds[8192];            // 128 KB: [kk 0..63][nrow 0..31][hi 0..3]
  __shared__ f32x4 pbuf[2][4][2][64];      // 16 KB partial double-buffer
  const int tid = threadIdx.x;
  const int bid = blockIdx.x;
  const int layer = bid >> 7;
  const int g = bid & 127;

  const unsigned short* Ws = layer ? W1s : W0s;
  const float* bias = layer ? b1 : b0;
  int* const cnt0 = cnt;                  // cnt0[s], stride 512 ints (8 sub-lines)
  int* const cnt1 = cnt + (TT << 9);      // cnt1[s], stride 512 ints

  // ---- stage weight slice once: linear 128KB copy ----
  {
    const short8* wsrc = (const short8*)(Ws + ((size_t)g << 16));
#pragma unroll
    for (int it = 0; it < 16; it++)
      wlds[tid + (it << 9)] = wsrc[tid + (it << 9)];
  }

  // ---- wave / lane mapping ----
  const int lane = tid & 63;
  const int w  = tid >> 6;        // 0..7
  const bool isA = (w < 4);
  const int mt = w & 3;           // m-tile (batch)
  const int m0 = mt << 4;
  const int n  = lane & 15;       // batch row within tile (C column)
  const int hi = lane >> 4;       // k-subchunk for operands; h-col within 4 for C
  const short8* bbase0 = wlds + ((n << 2) + hi);          // n-tile 0 rows 0..15
  const short8* bbase1 = wlds + (((16 + n) << 2) + hi);   // n-tile 1 rows 16..31
  const int m = m0 + n;                                   // this lane's batch row
  const int rowoff = (m << 10) + (hi << 3);               // x row base (row-major)
  const int bro = ((hi << 6) + m) << 3;                   // blocked h base: frag kk at bro + kk*2048
  const int col0 = (g << 3) + hi;                         // h-col, n-tile 0
  const int col1 = col0 + 4;                              // h-col, n-tile 1

  unsigned short* const myhist = (layer == 0) ? h0hist : h1hist;
  int* const mycnt = (layer == 0) ? cnt0 : cnt1;

  // ---- B-wave state: 4 gate biases per n-tile + c registers ----
  float bq[2][4];
  float creg[2];
  if (!isA) {
#pragma unroll
    for (int nt2 = 0; nt2 < 2; nt2++) {
      int col = nt2 ? col1 : col0;
#pragma unroll
      for (int qg = 0; qg < 4; qg++)
        bq[nt2][qg] = bias[(qg << 10) + col];
      creg[nt2] = c0in[(size_t)layer * BH + (m << 10) + col];
    }
  }
  __syncthreads();   // weights staged

  // ---- prologue: A-waves compute partial[0] + prefetch iter-0 operand ----
  short8 xa[16], xb[16];   // A cross-step prefetch registers (128 VGPR)
  if (isA) {
    if (layer == 1) {
      if (lane == 0) poll128(cnt0);      // h0hist[1] ready
      asm volatile("" ::: "memory");
    }
    f32x4 a0 = {0.f, 0.f, 0.f, 0.f}, a1 = {0.f, 0.f, 0.f, 0.f};
    if (layer == 0) {
      const unsigned short* asrc = xbf + rowoff;
      short8 ha[8];
#pragma unroll
      for (int j = 0; j < 8; j++) ha[j] = *(const short8*)(asrc + (j << 5));
#pragma unroll
      for (int blk = 0; blk < 4; blk++)
#pragma unroll
        for (int j = 0; j < 8; j++) {
          int kk = (blk << 3) + j;
          a0 = __builtin_amdgcn_mfma_f32_16x16x32_bf16(bbase0[kk << 7], ha[j], a0, 0, 0, 0);
          a1 = __builtin_amdgcn_mfma_f32_16x16x32_bf16(bbase1[kk << 7], ha[j], a1, 0, 0, 0);
          if (blk < 3) ha[j] = *(const short8*)(asrc + ((kk + 8) << 5));
        }
    } else {
      const unsigned short* asrc = h0hist + (size_t)BH + bro;   // slot 1, blocked
      short8 ha[8];
#pragma unroll
      for (int j = 0; j < 8; j++) ha[j] = *(const short8*)(asrc + (j << 11));
#pragma unroll
      for (int blk = 0; blk < 4; blk++)
#pragma unroll
        for (int j = 0; j < 8; j++) {
          int kk = (blk << 3) + j;
          a0 = __builtin_amdgcn_mfma_f32_16x16x32_bf16(bbase0[kk << 7], ha[j], a0, 0, 0, 0);
          a1 = __builtin_amdgcn_mfma_f32_16x16x32_bf16(bbase1[kk << 7], ha[j], a1, 0, 0, 0);
          if (blk < 3) ha[j] = *(const short8*)(asrc + ((kk + 8) << 11));
        }
    }
    pbuf[0][mt][0][lane] = a0;
    pbuf[0][mt][1][lane] = a1;
    // prefetch operand for iter-0 A-compute (target step 1)
    if (layer == 0) {
      const unsigned short* asrc = xbf + (size_t)BH + rowoff;       // x[1]
#pragma unroll
      for (int j = 0; j < 16; j++) xa[j] = *(const short8*)(asrc + (j << 5));
#pragma unroll
      for (int j = 0; j < 16; j++) xb[j] = *(const short8*)(asrc + ((16 + j) << 5));
    } else {
      if (lane == 0) poll128(cnt0 + (1 << 9));                      // cnt0[1]
      asm volatile("" ::: "memory");
      const unsigned short* asrc = h0hist + (size_t)2 * BH + bro;   // slot 2
#pragma unroll
      for (int j = 0; j < 16; j++) xa[j] = *(const short8*)(asrc + (j << 11));
#pragma unroll
      for (int j = 0; j < 16; j++) xb[j] = *(const short8*)(asrc + ((16 + j) << 11));
    }
  }
  __syncthreads();   // partial[0] sealed

  for (int s = 0; s < TT; s++) {
    if (isA) {
      // ---- consume prefetched operand -> partial[s+1] ----
      if (s + 1 < TT) {
        f32x4 a0 = {0.f, 0.f, 0.f, 0.f}, a1 = {0.f, 0.f, 0.f, 0.f};
#pragma unroll
        for (int j = 0; j < 16; j++) {
          a0 = __builtin_amdgcn_mfma_f32_16x16x32_bf16(bbase0[j << 7], xa[j], a0, 0, 0, 0);
          a1 = __builtin_amdgcn_mfma_f32_16x16x32_bf16(bbase1[j << 7], xa[j], a1, 0, 0, 0);
        }
#pragma unroll
        for (int j = 0; j < 16; j++) {
          a0 = __builtin_amdgcn_mfma_f32_16x16x32_bf16(bbase0[(16 + j) << 7], xb[j], a0, 0, 0, 0);
          a1 = __builtin_amdgcn_mfma_f32_16x16x32_bf16(bbase1[(16 + j) << 7], xb[j], a1, 0, 0, 0);
        }
        int buf = (s + 1) & 1;
        pbuf[buf][mt][0][lane] = a0;
        pbuf[buf][mt][1][lane] = a1;
      }
      // ---- issue prefetch for step s+2's A-compute (lands across the barrier) ----
      if (s + 2 < TT) {
        if (layer == 0) {
          const unsigned short* asrc = xbf + (size_t)(s + 2) * BH + rowoff;
#pragma unroll
          for (int j = 0; j < 16; j++) xa[j] = *(const short8*)(asrc + (j << 5));
#pragma unroll
          for (int j = 0; j < 16; j++) xb[j] = *(const short8*)(asrc + ((16 + j) << 5));
        } else {
          if (lane == 0) poll128(cnt0 + ((s + 2) << 9));   // h0hist[s+3] ready
          asm volatile("" ::: "memory");
          const unsigned short* asrc = h0hist + (size_t)(s + 3) * BH + bro;
#pragma unroll
          for (int j = 0; j < 16; j++) xa[j] = *(const short8*)(asrc + (j << 11));
#pragma unroll
          for (int j = 0; j < 16; j++) xb[j] = *(const short8*)(asrc + ((16 + j) << 11));
        }
      }
    } else {
      // ---- B tight wait: lane0 of THIS wave polls split counters directly ----
      if (s >= 1) {
        if (lane == 0) poll128(mycnt + ((s - 1) << 9));
        asm volatile("" ::: "memory");   // no load hoisting above the spin
      }
      // ---- recurrent GEMM: h[s] (blocked) x second K-half (8-deep rolling) ----
      f32x4 acc0 = pbuf[s & 1][mt][0][lane];
      f32x4 acc1 = pbuf[s & 1][mt][1][lane];
      const unsigned short* inB = myhist + (size_t)s * BH + bro;
      short8 ha[8];
#pragma unroll
      for (int j = 0; j < 8; j++) ha[j] = *(const short8*)(inB + (j << 11));
#pragma unroll
      for (int blk = 0; blk < 4; blk++)
#pragma unroll
        for (int j = 0; j < 8; j++) {
          int kk = (blk << 3) + j;
          acc0 = __builtin_amdgcn_mfma_f32_16x16x32_bf16(bbase0[(32 + kk) << 7], ha[j], acc0, 0, 0, 0);
          acc1 = __builtin_amdgcn_mfma_f32_16x16x32_bf16(bbase1[(32 + kk) << 7], ha[j], acc1, 0, 0, 0);
          if (blk < 3) ha[j] = *(const short8*)(inB + ((kk + 8) << 11));
        }

      // ---- epilogue: LANE-LOCAL cell update; blocked full-line sc1 h-stores ----
      unsigned short* hbb = myhist + (size_t)(s + 1) * BH + (((g << 6) + m) << 3);
#pragma unroll
      for (int nt2 = 0; nt2 < 2; nt2++) {
        f32x4 acc = nt2 ? acc1 : acc0;
        float ig = fsig(acc[0] + bq[nt2][0]);
        float fg = fsig(acc[1] + bq[nt2][1]);
        float gg = ftanhf(acc[2] + bq[nt2][2]);
        float og = fsig(acc[3] + bq[nt2][3]);
        float cn = ig * gg + fg * creg[nt2];
        float hn = og * ftanhf(cn);
        creg[nt2] = cn;
        GST(hbb + (nt2 << 2) + hi, f2bf(hn));
      }
      // B: own h-stores must be acked before the barrier (publish follows it)
      asm volatile("s_waitcnt vmcnt(0)" ::: "memory");
    }

    // ---- drain-free barrier: pbuf sealed via lgkmcnt; A prefetch crosses ----
    asm volatile("s_waitcnt lgkmcnt(0)" ::: "memory");
    __builtin_amdgcn_sched_barrier(0);
    __builtin_amdgcn_s_barrier();
    __builtin_amdgcn_sched_barrier(0);
    if (tid == 256) atomicAdd(mycnt + (s << 9) + ((g & 7) << 6), 1);

    // ---- final c (once, off the per-step path) ----
    if (!isA && s == TT - 1) {
#pragma unroll
      for (int nt2 = 0; nt2 < 2; nt2++) {
        const int col = nt2 ? col1 : col0;
        out[(size_t)TT * BH + (size_t)(2 + layer) * BH + (m << 10) + col] = creg[nt2];
      }
    }
  }
}

extern "C" void kernel_launch(void* const* d_in, const int* in_sizes, int n_in,
                              void* d_out, int out_size, void* d_ws, size_t ws_size,
                              hipStream_t stream) {
  (void)in_sizes; (void)n_in; (void)out_size; (void)ws_size;
  const float* x    = (const float*)d_in[0];
  const float* h0in = (const float*)d_in[1];
  const float* c0in = (const float*)d_in[2];
  const float* W0   = (const float*)d_in[3];
  const float* b0   = (const float*)d_in[4];
  const float* W1   = (const float*)d_in[5];
  const float* b1   = (const float*)d_in[6];
  float* out = (float*)d_out;

  char* ws = (char*)d_ws;
  const size_t HIST = (size_t)(TT + 1) * BH * sizeof(unsigned short);  // 67,239,936 B
  unsigned short* Xbf    = (unsigned short*)(ws);                      // 64 MB
  unsigned short* W0s    = (unsigned short*)(ws + 67108864);           // 16 MB
  unsigned short* W1s    = (unsigned short*)(ws + 83886080);           // 16 MB
  unsigned short* h0hist = (unsigned short*)(ws + 100663296);          // 64.1 MB
  unsigned short* h1hist = (unsigned short*)(ws + 100663296 + HIST);   // 64.1 MB
  int* cnt               = (int*)(ws + 100663296 + 2 * HIST);          // 2 MB counters

  const size_t CNT_BYTES = (size_t)2 * TT * 512 * sizeof(int);
  hipMemsetAsync(cnt, 0, CNT_BYTES, stream);
  cvt_x_kernel<<<2048, 256, 0, stream>>>(x, Xbf);
  cvt_w_kernel<<<4096, 256, 0, stream>>>(W0, W0s);
  cvt_w_kernel<<<4096, 256, 0, stream>>>(W1, W1s);
  init_state_kernel<<<256, 256, 0, stream>>>(h0in, h0hist, h1hist);

  lstm_persist<<<256, 512, 0, stream>>>(W0s, W1s, b0, b1, Xbf,
                                        h0hist, h1hist, c0in, out, cnt);

  finalize_kernel<<<2048, 256, 0, stream>>>(h0hist, h1hist, out);
}

// Round 20
// 4715.138 us; speedup vs baseline: 1.1169x; 1.1169x over previous
//
#include <hip/hip_runtime.h>
#include <hip/hip_bf16.h>
#include <stdint.h>

// Problem constants (fixed by the reference): T=512, B=64, IN=H=1024, L=2
#define TT 512
#define BB 64
#define HH 1024
#define BH 65536    // B*H elements
#define KD 2048     // IN+H == H+H

typedef __attribute__((ext_vector_type(8))) short short8;
typedef __attribute__((ext_vector_type(4))) float f32x4;

__device__ __forceinline__ unsigned short f2bf(float f) {
  union { float f; unsigned int u; } v; v.f = f;
  unsigned int r = v.u + 0x7fffu + ((v.u >> 16) & 1u);  // RNE
  return (unsigned short)(r >> 16);
}
__device__ __forceinline__ float bf2f(unsigned short u) {
  union { unsigned int u; float f; } v; v.u = ((unsigned int)u) << 16; return v.f;
}
__device__ __forceinline__ float fsig(float x)  { return 1.0f / (1.0f + __expf(-x)); }
__device__ __forceinline__ float ftanhf(float x){ return 1.0f - 2.0f / (__expf(2.0f * x) + 1.0f); }

// ---------------- x -> bf16 (row-major) ----------------
__global__ void cvt_x_kernel(const float* __restrict__ x, unsigned short* __restrict__ xbf) {
  const int n4 = (TT * BB * 1024) / 4;
  int stride = gridDim.x * blockDim.x;
  for (int i = blockIdx.x * blockDim.x + threadIdx.x; i < n4; i += stride) {
    float4 v = ((const float4*)x)[i];
    unsigned long long p = (unsigned long long)f2bf(v.x)
        | ((unsigned long long)f2bf(v.y) << 16)
        | ((unsigned long long)f2bf(v.z) << 32)
        | ((unsigned long long)f2bf(v.w) << 48);
    ((unsigned long long*)xbf)[i] = p;
  }
}

// ---------------- W [4096][2048] f32 -> bf16, LDS-image layout (TRANSPOSED-C perm) ----
// Ws[g][kk 0..63][nrow 0..31][hi 0..3][8 bf16]; nrow: nt=nrow>>4, q=nrow&3, jl=(nrow>>2)&3
//   -> W row = q*1024 + g*8 + nt*4 + jl ; kk<32: k=kk*32+hi*8 ; kk>=32: k=1024+(kk-32)*32+hi*8
__global__ void cvt_w_kernel(const float* __restrict__ W, unsigned short* __restrict__ Ws) {
  int idx = blockIdx.x * blockDim.x + threadIdx.x;   // < 1,048,576
  int hi = idx & 3;
  int nr = (idx >> 2) & 31;
  int kk = (idx >> 7) & 63;
  int g  = idx >> 13;
  int q  = nr & 3;
  int jl = (nr >> 2) & 3;
  int nt = nr >> 4;
  int grow = (q << 10) + (g << 3) + (nt << 2) + jl;
  int k = ((kk < 32) ? (kk << 5) : (1024 + ((kk - 32) << 5))) + (hi << 3);
  const float* src = W + (size_t)grow * KD + k;
  float4 v0 = ((const float4*)src)[0];
  float4 v1 = ((const float4*)src)[1];
  unsigned long long p0 = (unsigned long long)f2bf(v0.x)
      | ((unsigned long long)f2bf(v0.y) << 16)
      | ((unsigned long long)f2bf(v0.z) << 32)
      | ((unsigned long long)f2bf(v0.w) << 48);
  unsigned long long p1 = (unsigned long long)f2bf(v1.x)
      | ((unsigned long long)f2bf(v1.y) << 16)
      | ((unsigned long long)f2bf(v1.z) << 32)
      | ((unsigned long long)f2bf(v1.w) << 48);
  unsigned long long* dst = (unsigned long long*)(Ws + ((size_t)g << 16) + (kk << 10) + (nr << 5) + (hi << 3));
  dst[0] = p0;
  dst[1] = p1;
}

// ---------------- initial h -> hist slot 0 (BLOCKED layout [cb][m][8]) ----------------
__global__ void init_state_kernel(const float* __restrict__ h0in,
                                  unsigned short* h0s0, unsigned short* h1s0) {
  int i = blockIdx.x * blockDim.x + threadIdx.x;  // < BH
  int m = i >> 10, c = i & 1023;
  int dst = ((c >> 3) << 9) + (m << 3) + (c & 7);
  h0s0[dst] = f2bf(h0in[i]);
  h1s0[dst] = f2bf(h0in[BH + i]);
}

// ---------------- post-pass: blocked bf16 hist -> row-major fp32 out ----------------
__global__ void finalize_kernel(const unsigned short* __restrict__ h0hist,
                                const unsigned short* __restrict__ h1hist,
                                float* __restrict__ out) {
  const size_t NCH = (size_t)(TT + 2) * (BH / 8);
  size_t stride = (size_t)gridDim.x * blockDim.x;
  for (size_t i = (size_t)blockIdx.x * blockDim.x + threadIdx.x; i < NCH; i += stride) {
    int p  = (int)(i >> 13);     // BH/8 = 8192
    int ci = (int)(i & 8191);
    int cb = ci >> 6, m = ci & 63;
    const unsigned short* src;
    size_t dbase;
    if (p < TT)       { src = h1hist + (size_t)(p + 1) * BH; dbase = (size_t)p * BH; }
    else if (p == TT) { src = h0hist + (size_t)TT * BH;      dbase = (size_t)TT * BH; }
    else              { src = h1hist + (size_t)TT * BH;      dbase = (size_t)TT * BH + BH; }
    const unsigned short* sp = src + ((size_t)ci << 3);
    ushort4 v0 = ((const ushort4*)sp)[0];
    ushort4 v1 = ((const ushort4*)sp)[1];
    float* dp = out + dbase + (m << 10) + (cb << 3);
    *(float4*)(dp)     = make_float4(bf2f(v0.x), bf2f(v0.y), bf2f(v0.z), bf2f(v0.w));
    *(float4*)(dp + 4) = make_float4(bf2f(v1.x), bf2f(v1.y), bf2f(v1.z), bf2f(v1.w));
  }
}

#define GLD(p)    __hip_atomic_load((p),  __ATOMIC_RELAXED, __HIP_MEMORY_SCOPE_AGENT)
#define GST(p, v) __hip_atomic_store((p), (v), __ATOMIC_RELAXED, __HIP_MEMORY_SCOPE_AGENT)

// spin until the 8 sub-counters (256B apart) sum to 128
__device__ __forceinline__ void poll128(int* base) {
  for (;;) {
    int s = 0;
#pragma unroll
    for (int j = 0; j < 8; j++)
      s += GLD(base + (j << 6));
    if (s >= 128) return;
    __builtin_amdgcn_s_sleep(1);
  }
}

// ---------------- persistent 2-layer LSTM, v15: r18 + x LLC/L2 warming ----------------
// 256 blocks x 512 threads, 1 block/CU. Blocks 0-127: layer0, 128-255: layer1.
// TRANSPOSED MFMA, lane-local epilogue, BLOCKED h hist (full-line stores).
// Waves 0-3 (A): r18 rolling-8 compute of partial[s+1]. NEW: L0 A-waves issue
// 4 plain dword loads at iteration top covering their 32KB of x[s+5] (one
// touch per 128B line). Plain loads fill LLC AND the local XCD L2; the
// consumer is this same CU, so 4 iterations later the compute loads hit L2
// (~200cy) instead of HBM (~900cy, the 4-round long pole: working set ~224MB
// at ~90% LLC occupancy thrashes ~7.5% of x lines per pass). Warm regs are
// asm-consumed at iteration end (~4us later -> waitcnt free; prevents DCE).
// Waves 4-7 (B): unchanged tight recurrence.
// Sync (r18): per-step __syncthreads -> tid0 atomicAdd 8-way-split cnt[L][s].
__global__ __launch_bounds__(512, 2) void lstm_persist(
    const unsigned short* __restrict__ W0s, const unsigned short* __restrict__ W1s,
    const float* __restrict__ b0, const float* __restrict__ b1,
    const unsigned short* __restrict__ xbf,
    unsigned short* h0hist, unsigned short* h1hist,
    const float* __restrict__ c0in, float* out, int* cnt)
{
  __shared__ short8 wlds[8192];            // 128 KB: [kk 0..63][nrow 0..31][hi 0..3]
  __shared__ f32x4 pbuf[2][4][2][64];      // 16 KB partial double-buffer
  const int tid = threadIdx.x;
  const int bid = blockIdx.x;
  const int layer = bid >> 7;
  const int g = bid & 127;

  const unsigned short* Ws = layer ? W1s : W0s;
  const float* bias = layer ? b1 : b0;
  int* const cnt0 = cnt;                  // cnt0[s], stride 512 ints (8 sub-lines)
  int* const cnt1 = cnt + (TT << 9);      // cnt1[s], stride 512 ints

  // ---- stage weight slice once: linear 128KB copy ----
  {
    const short8* wsrc = (const short8*)(Ws + ((size_t)g << 16));
#pragma unroll
    for (int it = 0; it < 16; it++)
      wlds[tid + (it << 9)] = wsrc[tid + (it << 9)];
  }

  // ---- wave / lane mapping ----
  const int lane = tid & 63;
  const int w  = tid >> 6;        // 0..7
  const bool isA = (w < 4);
  const int mt = w & 3;           // m-tile (batch)
  const int m0 = mt << 4;
  const int n  = lane & 15;       // batch row within tile (C column)
  const int hi = lane >> 4;       // k-subchunk for operands; h-col within 4 for C
  const short8* bbase0 = wlds + ((n << 2) + hi);          // n-tile 0 rows 0..15
  const short8* bbase1 = wlds + (((16 + n) << 2) + hi);   // n-tile 1 rows 16..31
  const int m = m0 + n;                                   // this lane's batch row
  const int rowoff = (m << 10) + (hi << 3);               // x row base (row-major)
  const int bro = ((hi << 6) + m) << 3;                   // blocked h base: frag kk at bro + kk*2048
  const int col0 = (g << 3) + hi;                         // h-col, n-tile 0
  const int col1 = col0 + 4;                              // h-col, n-tile 1

  unsigned short* const myhist = (layer == 0) ? h0hist : h1hist;
  int* const mycnt = (layer == 0) ? cnt0 : cnt1;

  // ---- B-wave state: 4 gate biases per n-tile + c registers ----
  float bq[2][4];
  float creg[2];
  if (!isA) {
#pragma unroll
    for (int nt2 = 0; nt2 < 2; nt2++) {
      int col = nt2 ? col1 : col0;
#pragma unroll
      for (int qg = 0; qg < 4; qg++)
        bq[nt2][qg] = bias[(qg << 10) + col];
      creg[nt2] = c0in[(size_t)layer * BH + (m << 10) + col];
    }
  }
  __syncthreads();   // weights staged

  // ---- prologue: A-waves compute partial[0] (L1 gated lane0-poll cnt0[0]) ----
  if (isA) {
    if (layer == 1) {
      if (lane == 0) poll128(cnt0);
      asm volatile("" ::: "memory");
    }
    f32x4 a0 = {0.f, 0.f, 0.f, 0.f}, a1 = {0.f, 0.f, 0.f, 0.f};
    if (layer == 0) {
      const unsigned short* asrc = xbf + rowoff;
      short8 ha[8];
#pragma unroll
      for (int j = 0; j < 8; j++) ha[j] = *(const short8*)(asrc + (j << 5));
#pragma unroll
      for (int blk = 0; blk < 4; blk++)
#pragma unroll
        for (int j = 0; j < 8; j++) {
          int kk = (blk << 3) + j;
          a0 = __builtin_amdgcn_mfma_f32_16x16x32_bf16(bbase0[kk << 7], ha[j], a0, 0, 0, 0);
          a1 = __builtin_amdgcn_mfma_f32_16x16x32_bf16(bbase1[kk << 7], ha[j], a1, 0, 0, 0);
          if (blk < 3) ha[j] = *(const short8*)(asrc + ((kk + 8) << 5));
        }
    } else {
      const unsigned short* asrc = h0hist + (size_t)BH + bro;   // slot 1, blocked
      short8 ha[8];
#pragma unroll
      for (int j = 0; j < 8; j++) ha[j] = *(const short8*)(asrc + (j << 11));
#pragma unroll
      for (int blk = 0; blk < 4; blk++)
#pragma unroll
        for (int j = 0; j < 8; j++) {
          int kk = (blk << 3) + j;
          a0 = __builtin_amdgcn_mfma_f32_16x16x32_bf16(bbase0[kk << 7], ha[j], a0, 0, 0, 0);
          a1 = __builtin_amdgcn_mfma_f32_16x16x32_bf16(bbase1[kk << 7], ha[j], a1, 0, 0, 0);
          if (blk < 3) ha[j] = *(const short8*)(asrc + ((kk + 8) << 11));
        }
    }
    pbuf[0][mt][0][lane] = a0;
    pbuf[0][mt][1][lane] = a1;
  }
  __syncthreads();   // partial[0] sealed

  for (int s = 0; s < TT; s++) {
    if (isA) {
      // ---- NEW: warm x[s+5] lines into LLC + local L2 (L0 only) ----
      unsigned int wm0 = 0, wm1 = 0, wm2 = 0, wm3 = 0;
      const bool dowarm = (layer == 0) && (s + 5 < TT);
      if (dowarm) {
        const unsigned int* wp = (const unsigned int*)(xbf + (size_t)(s + 5) * BH + (m0 << 10));
        wm0 = wp[(lane)       << 5];    // one dword per 128B line, 256 lines/wave
        wm1 = wp[(64  + lane) << 5];
        wm2 = wp[(128 + lane) << 5];
        wm3 = wp[(192 + lane) << 5];
      }
      // ---- A-compute for step s+1 into pbuf[(s+1)&1] ----
      if (s + 1 < TT) {
        f32x4 a0 = {0.f, 0.f, 0.f, 0.f}, a1 = {0.f, 0.f, 0.f, 0.f};
        if (layer == 0) {
          const unsigned short* asrc = xbf + (size_t)(s + 1) * BH + rowoff;
          short8 ha[8];
#pragma unroll
          for (int j = 0; j < 8; j++) ha[j] = *(const short8*)(asrc + (j << 5));
#pragma unroll
          for (int blk = 0; blk < 4; blk++)
#pragma unroll
            for (int j = 0; j < 8; j++) {
              int kk = (blk << 3) + j;
              a0 = __builtin_amdgcn_mfma_f32_16x16x32_bf16(bbase0[kk << 7], ha[j], a0, 0, 0, 0);
              a1 = __builtin_amdgcn_mfma_f32_16x16x32_bf16(bbase1[kk << 7], ha[j], a1, 0, 0, 0);
              if (blk < 3) ha[j] = *(const short8*)(asrc + ((kk + 8) << 5));
            }
        } else {
          if (lane == 0) poll128(cnt0 + ((s + 1) << 9));   // h0hist[s+2] ready
          asm volatile("" ::: "memory");
          const unsigned short* asrc = h0hist + (size_t)(s + 2) * BH + bro;  // blocked
          short8 ha[8];
#pragma unroll
          for (int j = 0; j < 8; j++) ha[j] = *(const short8*)(asrc + (j << 11));
#pragma unroll
          for (int blk = 0; blk < 4; blk++)
#pragma unroll
            for (int j = 0; j < 8; j++) {
              int kk = (blk << 3) + j;
              a0 = __builtin_amdgcn_mfma_f32_16x16x32_bf16(bbase0[kk << 7], ha[j], a0, 0, 0, 0);
              a1 = __builtin_amdgcn_mfma_f32_16x16x32_bf16(bbase1[kk << 7], ha[j], a1, 0, 0, 0);
              if (blk < 3) ha[j] = *(const short8*)(asrc + ((kk + 8) << 11));
            }
        }
        int buf = (s + 1) & 1;
        pbuf[buf][mt][0][lane] = a0;
        pbuf[buf][mt][1][lane] = a1;
      }
      // consume warm regs (loads returned ~a full step ago; prevents DCE)
      if (dowarm) asm volatile("" :: "v"(wm0), "v"(wm1), "v"(wm2), "v"(wm3));
    } else {
      // ---- B tight wait: lane0 of THIS wave polls split counters directly ----
      if (s >= 1) {
        if (lane == 0) poll128(mycnt + ((s - 1) << 9));
        asm volatile("" ::: "memory");   // no load hoisting above the spin
      }
      // ---- recurrent GEMM: h[s] (blocked) x second K-half (8-deep rolling) ----
      f32x4 acc0 = pbuf[s & 1][mt][0][lane];
      f32x4 acc1 = pbuf[s & 1][mt][1][lane];
      const unsigned short* inB = myhist + (size_t)s * BH + bro;
      short8 ha[8];
#pragma unroll
      for (int j = 0; j < 8; j++) ha[j] = *(const short8*)(inB + (j << 11));
#pragma unroll
      for (int blk = 0; blk < 4; blk++)
#pragma unroll
        for (int j = 0; j < 8; j++) {
          int kk = (blk << 3) + j;
          acc0 = __builtin_amdgcn_mfma_f32_16x16x32_bf16(bbase0[(32 + kk) << 7], ha[j], acc0, 0, 0, 0);
          acc1 = __builtin_amdgcn_mfma_f32_16x16x32_bf16(bbase1[(32 + kk) << 7], ha[j], acc1, 0, 0, 0);
          if (blk < 3) ha[j] = *(const short8*)(inB + ((kk + 8) << 11));
        }

      // ---- epilogue: LANE-LOCAL cell update; blocked full-line sc1 h-stores ----
      unsigned short* hbb = myhist + (size_t)(s + 1) * BH + (((g << 6) + m) << 3);
#pragma unroll
      for (int nt2 = 0; nt2 < 2; nt2++) {
        f32x4 acc = nt2 ? acc1 : acc0;
        float ig = fsig(acc[0] + bq[nt2][0]);
        float fg = fsig(acc[1] + bq[nt2][1]);
        float gg = ftanhf(acc[2] + bq[nt2][2]);
        float og = fsig(acc[3] + bq[nt2][3]);
        float cn = ig * gg + fg * creg[nt2];
        float hn = og * ftanhf(cn);
        creg[nt2] = cn;
        GST(hbb + (nt2 << 2) + hi, f2bf(hn));
      }
    }

    // ---- end of step: seal pbuf[(s+1)&1], drain B h-stores, publish ----
    __syncthreads();
    if (tid == 0) atomicAdd(mycnt + (s << 9) + ((g & 7) << 6), 1);

    // ---- final c (once, off the per-step path) ----
    if (!isA && s == TT - 1) {
#pragma unroll
      for (int nt2 = 0; nt2 < 2; nt2++) {
        const int col = nt2 ? col1 : col0;
        out[(size_t)TT * BH + (size_t)(2 + layer) * BH + (m << 10) + col] = creg[nt2];
      }
    }
  }
}

extern "C" void kernel_launch(void* const* d_in, const int* in_sizes, int n_in,
                              void* d_out, int out_size, void* d_ws, size_t ws_size,
                              hipStream_t stream) {
  (void)in_sizes; (void)n_in; (void)out_size; (void)ws_size;
  const float* x    = (const float*)d_in[0];
  const float* h0in = (const float*)d_in[1];
  const float* c0in = (const float*)d_in[2];
  const float* W0   = (const float*)d_in[3];
  const float* b0   = (const float*)d_in[4];
  const float* W1   = (const float*)d_in[5];
  const float* b1   = (const float*)d_in[6];
  float* out = (float*)d_out;

  char* ws = (char*)d_ws;
  const size_t HIST = (size_t)(TT + 1) * BH * sizeof(unsigned short);  // 67,239,936 B
  unsigned short* Xbf    = (unsigned short*)(ws);                      // 64 MB
  unsigned short* W0s    = (unsigned short*)(ws + 67108864);           // 16 MB
  unsigned short* W1s    = (unsigned short*)(ws + 83886080);           // 16 MB
  unsigned short* h0hist = (unsigned short*)(ws + 100663296);          // 64.1 MB
  unsigned short* h1hist = (unsigned short*)(ws + 100663296 + HIST);   // 64.1 MB
  int* cnt               = (int*)(ws + 100663296 + 2 * HIST);          // 2 MB counters

  const size_t CNT_BYTES = (size_t)2 * TT * 512 * sizeof(int);
  hipMemsetAsync(cnt, 0, CNT_BYTES, stream);
  cvt_x_kernel<<<2048, 256, 0, stream>>>(x, Xbf);
  cvt_w_kernel<<<4096, 256, 0, stream>>>(W0, W0s);
  cvt_w_kernel<<<4096, 256, 0, stream>>>(W1, W1s);
  init_state_kernel<<<256, 256, 0, stream>>>(h0in, h0hist, h1hist);

  lstm_persist<<<256, 512, 0, stream>>>(W0s, W1s, b0, b1, Xbf,
                                        h0hist, h1hist, c0in, out, cnt);

  finalize_kernel<<<2048, 256, 0, stream>>>(h0hist, h1hist, out);
}

// Round 21
// 4280.152 us; speedup vs baseline: 1.2304x; 1.1016x over previous
//
#include <hip/hip_runtime.h>
#include <hip/hip_bf16.h>
#include <stdint.h>

// Problem constants (fixed by the reference): T=512, B=64, IN=H=1024, L=2
#define TT 512
#define BB 64
#define HH 1024
#define BH 65536    // B*H elements
#define KD 2048     // IN+H == H+H

typedef __attribute__((ext_vector_type(8))) short short8;
typedef __attribute__((ext_vector_type(4))) float f32x4;

__device__ __forceinline__ unsigned short f2bf(float f) {
  union { float f; unsigned int u; } v; v.f = f;
  unsigned int r = v.u + 0x7fffu + ((v.u >> 16) & 1u);  // RNE
  return (unsigned short)(r >> 16);
}
__device__ __forceinline__ float bf2f(unsigned short u) {
  union { unsigned int u; float f; } v; v.u = ((unsigned int)u) << 16; return v.f;
}
__device__ __forceinline__ float fsig(float x)  { return 1.0f / (1.0f + __expf(-x)); }
__device__ __forceinline__ float ftanhf(float x){ return 1.0f - 2.0f / (__expf(2.0f * x) + 1.0f); }

// ---------------- x -> bf16 (row-major) ----------------
__global__ void cvt_x_kernel(const float* __restrict__ x, unsigned short* __restrict__ xbf) {
  const int n4 = (TT * BB * 1024) / 4;
  int stride = gridDim.x * blockDim.x;
  for (int i = blockIdx.x * blockDim.x + threadIdx.x; i < n4; i += stride) {
    float4 v = ((const float4*)x)[i];
    unsigned long long p = (unsigned long long)f2bf(v.x)
        | ((unsigned long long)f2bf(v.y) << 16)
        | ((unsigned long long)f2bf(v.z) << 32)
        | ((unsigned long long)f2bf(v.w) << 48);
    ((unsigned long long*)xbf)[i] = p;
  }
}

// ---------------- W [4096][2048] f32 -> bf16, LDS-image layout (TRANSPOSED-C perm) ----
// Ws[g][kk 0..63][nrow 0..31][hi 0..3][8 bf16]; nrow: nt=nrow>>4, q=nrow&3, jl=(nrow>>2)&3
//   -> W row = q*1024 + g*8 + nt*4 + jl ; kk<32: k=kk*32+hi*8 ; kk>=32: k=1024+(kk-32)*32+hi*8
__global__ void cvt_w_kernel(const float* __restrict__ W, unsigned short* __restrict__ Ws) {
  int idx = blockIdx.x * blockDim.x + threadIdx.x;   // < 1,048,576
  int hi = idx & 3;
  int nr = (idx >> 2) & 31;
  int kk = (idx >> 7) & 63;
  int g  = idx >> 13;
  int q  = nr & 3;
  int jl = (nr >> 2) & 3;
  int nt = nr >> 4;
  int grow = (q << 10) + (g << 3) + (nt << 2) + jl;
  int k = ((kk < 32) ? (kk << 5) : (1024 + ((kk - 32) << 5))) + (hi << 3);
  const float* src = W + (size_t)grow * KD + k;
  float4 v0 = ((const float4*)src)[0];
  float4 v1 = ((const float4*)src)[1];
  unsigned long long p0 = (unsigned long long)f2bf(v0.x)
      | ((unsigned long long)f2bf(v0.y) << 16)
      | ((unsigned long long)f2bf(v0.z) << 32)
      | ((unsigned long long)f2bf(v0.w) << 48);
  unsigned long long p1 = (unsigned long long)f2bf(v1.x)
      | ((unsigned long long)f2bf(v1.y) << 16)
      | ((unsigned long long)f2bf(v1.z) << 32)
      | ((unsigned long long)f2bf(v1.w) << 48);
  unsigned long long* dst = (unsigned long long*)(Ws + ((size_t)g << 16) + (kk << 10) + (nr << 5) + (hi << 3));
  dst[0] = p0;
  dst[1] = p1;
}

// ---------------- initial h -> hist slot 0 (BLOCKED layout [cb][m][8]) ----------------
__global__ void init_state_kernel(const float* __restrict__ h0in,
                                  unsigned short* h0s0, unsigned short* h1s0) {
  int i = blockIdx.x * blockDim.x + threadIdx.x;  // < BH
  int m = i >> 10, c = i & 1023;
  int dst = ((c >> 3) << 9) + (m << 3) + (c & 7);
  h0s0[dst] = f2bf(h0in[i]);
  h1s0[dst] = f2bf(h0in[BH + i]);
}

// ---------------- post-pass: blocked bf16 hist -> row-major fp32 out ----------------
__global__ void finalize_kernel(const unsigned short* __restrict__ h0hist,
                                const unsigned short* __restrict__ h1hist,
                                float* __restrict__ out) {
  const size_t NCH = (size_t)(TT + 2) * (BH / 8);
  size_t stride = (size_t)gridDim.x * blockDim.x;
  for (size_t i = (size_t)blockIdx.x * blockDim.x + threadIdx.x; i < NCH; i += stride) {
    int p  = (int)(i >> 13);     // BH/8 = 8192
    int ci = (int)(i & 8191);
    int cb = ci >> 6, m = ci & 63;
    const unsigned short* src;
    size_t dbase;
    if (p < TT)       { src = h1hist + (size_t)(p + 1) * BH; dbase = (size_t)p * BH; }
    else if (p == TT) { src = h0hist + (size_t)TT * BH;      dbase = (size_t)TT * BH; }
    else              { src = h1hist + (size_t)TT * BH;      dbase = (size_t)TT * BH + BH; }
    const unsigned short* sp = src + ((size_t)ci << 3);
    ushort4 v0 = ((const ushort4*)sp)[0];
    ushort4 v1 = ((const ushort4*)sp)[1];
    float* dp = out + dbase + (m << 10) + (cb << 3);
    *(float4*)(dp)     = make_float4(bf2f(v0.x), bf2f(v0.y), bf2f(v0.z), bf2f(v0.w));
    *(float4*)(dp + 4) = make_float4(bf2f(v1.x), bf2f(v1.y), bf2f(v1.z), bf2f(v1.w));
  }
}

#define GLD(p)    __hip_atomic_load((p),  __ATOMIC_RELAXED, __HIP_MEMORY_SCOPE_AGENT)
#define GST(p, v) __hip_atomic_store((p), (v), __ATOMIC_RELAXED, __HIP_MEMORY_SCOPE_AGENT)

// spin until the 8 sub-counters (256B apart) sum to 128  (L1-A cross-layer gate)
__device__ __forceinline__ void poll128(int* base) {
  for (;;) {
    int s = 0;
#pragma unroll
    for (int j = 0; j < 8; j++)
      s += GLD(base + (j << 6));
    if (s >= 128) return;
    __builtin_amdgcn_s_sleep(1);
  }
}

// ---------------- persistent 2-layer LSTM, v16: r18 + early tags + rolling-16 ----------------
// 256 blocks x 512 threads, 1 block/CU. Blocks 0-127: layer0, 128-255: layer1.
// TRANSPOSED MFMA, lane-local epilogue, BLOCKED h hist (full-line stores).
// INTRA-layer h readiness now via ring-4 per-(slot,mt,quad) TAG WORDS (64B
// lines): producer B-wave mt of block g drains its OWN sc1 h-stores
// (s_waitcnt vmcnt(0)) then lane0 byte-stores (s+1)&255 into byte g&3 of
// tag[(s+1)&3][mt][g>>2] — BEFORE the block barrier (signal ~1us earlier than
// the old barrier+atomicAdd+LLC-serialize chain). Consumer B-waves poll all
// 32 words CONCURRENTLY (one word per lane, per-lane spin -> 1 LLC RTT/round),
// natural consume order (FP sum order unchanged; absmax is the race canary).
// Intra-layer iter skew <=1 (all-to-all K dep) -> ring-4 exact match alias-free
// (r14's livelock was only the CROSS-layer equality gate; L1-A keeps monotone
// cnt0, published by L0 tid0 after the barrier as before).
// Rolling-16 loads (ha[16]) in A and B main loops: 4 dependent LLC rounds -> 2.
__global__ __launch_bounds__(512, 2) void lstm_persist(
    const unsigned short* __restrict__ W0s, const unsigned short* __restrict__ W1s,
    const float* __restrict__ b0, const float* __restrict__ b1,
    const unsigned short* __restrict__ xbf,
    unsigned short* h0hist, unsigned short* h1hist,
    const float* __restrict__ c0in, float* out, int* tags, int* cnt0)
{
  __shared__ short8 wlds[8192];            // 128 KB: [kk 0..63][nrow 0..31][hi 0..3]
  __shared__ f32x4 pbuf[2][4][2][64];      // 16 KB partial double-buffer
  const int tid = threadIdx.x;
  const int bid = blockIdx.x;
  const int layer = bid >> 7;
  const int g = bid & 127;

  const unsigned short* Ws = layer ? W1s : W0s;
  const float* bias = layer ? b1 : b0;
  int* const mytag = tags + (layer << 13);   // 8192 ints (32KB) per layer
  // tag word (ring r, mt, kq) at mytag + ((r*4+mt)<<9) + (kq<<4)   [64B lines]

  // ---- stage weight slice once: linear 128KB copy ----
  {
    const short8* wsrc = (const short8*)(Ws + ((size_t)g << 16));
#pragma unroll
    for (int it = 0; it < 16; it++)
      wlds[tid + (it << 9)] = wsrc[tid + (it << 9)];
  }

  // ---- wave / lane mapping ----
  const int lane = tid & 63;
  const int w  = tid >> 6;        // 0..7
  const bool isA = (w < 4);
  const int mt = w & 3;           // m-tile (batch)
  const int m0 = mt << 4;
  const int n  = lane & 15;       // batch row within tile (C column)
  const int hi = lane >> 4;       // k-subchunk for operands; h-col within 4 for C
  const short8* bbase0 = wlds + ((n << 2) + hi);          // n-tile 0 rows 0..15
  const short8* bbase1 = wlds + (((16 + n) << 2) + hi);   // n-tile 1 rows 16..31
  const int m = m0 + n;                                   // this lane's batch row
  const int rowoff = (m << 10) + (hi << 3);               // x row base (row-major)
  const int bro = ((hi << 6) + m) << 3;                   // blocked h base: frag kk at bro + kk*2048
  const int col0 = (g << 3) + hi;                         // h-col, n-tile 0
  const int col1 = col0 + 4;                              // h-col, n-tile 1

  unsigned short* const myhist = (layer == 0) ? h0hist : h1hist;

  // ---- B-wave state: 4 gate biases per n-tile + c registers ----
  float bq[2][4];
  float creg[2];
  if (!isA) {
#pragma unroll
    for (int nt2 = 0; nt2 < 2; nt2++) {
      int col = nt2 ? col1 : col0;
#pragma unroll
      for (int qg = 0; qg < 4; qg++)
        bq[nt2][qg] = bias[(qg << 10) + col];
      creg[nt2] = c0in[(size_t)layer * BH + (m << 10) + col];
    }
  }
  __syncthreads();   // weights staged

  // ---- prologue: A-waves compute partial[0] (L1 gated lane0-poll cnt0[0]) ----
  if (isA) {
    if (layer == 1) {
      if (lane == 0) poll128(cnt0);
      asm volatile("" ::: "memory");
    }
    f32x4 a0 = {0.f, 0.f, 0.f, 0.f}, a1 = {0.f, 0.f, 0.f, 0.f};
    if (layer == 0) {
      const unsigned short* asrc = xbf + rowoff;
      short8 ha[8];
#pragma unroll
      for (int j = 0; j < 8; j++) ha[j] = *(const short8*)(asrc + (j << 5));
#pragma unroll
      for (int blk = 0; blk < 4; blk++)
#pragma unroll
        for (int j = 0; j < 8; j++) {
          int kk = (blk << 3) + j;
          a0 = __builtin_amdgcn_mfma_f32_16x16x32_bf16(bbase0[kk << 7], ha[j], a0, 0, 0, 0);
          a1 = __builtin_amdgcn_mfma_f32_16x16x32_bf16(bbase1[kk << 7], ha[j], a1, 0, 0, 0);
          if (blk < 3) ha[j] = *(const short8*)(asrc + ((kk + 8) << 5));
        }
    } else {
      const unsigned short* asrc = h0hist + (size_t)BH + bro;   // slot 1, blocked
      short8 ha[8];
#pragma unroll
      for (int j = 0; j < 8; j++) ha[j] = *(const short8*)(asrc + (j << 11));
#pragma unroll
      for (int blk = 0; blk < 4; blk++)
#pragma unroll
        for (int j = 0; j < 8; j++) {
          int kk = (blk << 3) + j;
          a0 = __builtin_amdgcn_mfma_f32_16x16x32_bf16(bbase0[kk << 7], ha[j], a0, 0, 0, 0);
          a1 = __builtin_amdgcn_mfma_f32_16x16x32_bf16(bbase1[kk << 7], ha[j], a1, 0, 0, 0);
          if (blk < 3) ha[j] = *(const short8*)(asrc + ((kk + 8) << 11));
        }
    }
    pbuf[0][mt][0][lane] = a0;
    pbuf[0][mt][1][lane] = a1;
  }
  __syncthreads();   // partial[0] sealed

  for (int s = 0; s < TT; s++) {
    if (isA) {
      // ---- A-compute for step s+1 into pbuf[(s+1)&1] (rolling-16) ----
      if (s + 1 < TT) {
        f32x4 a0 = {0.f, 0.f, 0.f, 0.f}, a1 = {0.f, 0.f, 0.f, 0.f};
        if (layer == 0) {
          const unsigned short* asrc = xbf + (size_t)(s + 1) * BH + rowoff;
          short8 ha[16];
#pragma unroll
          for (int j = 0; j < 16; j++) ha[j] = *(const short8*)(asrc + (j << 5));
#pragma unroll
          for (int j = 0; j < 16; j++) {
            a0 = __builtin_amdgcn_mfma_f32_16x16x32_bf16(bbase0[j << 7], ha[j], a0, 0, 0, 0);
            a1 = __builtin_amdgcn_mfma_f32_16x16x32_bf16(bbase1[j << 7], ha[j], a1, 0, 0, 0);
            ha[j] = *(const short8*)(asrc + ((16 + j) << 5));
          }
#pragma unroll
          for (int j = 0; j < 16; j++) {
            a0 = __builtin_amdgcn_mfma_f32_16x16x32_bf16(bbase0[(16 + j) << 7], ha[j], a0, 0, 0, 0);
            a1 = __builtin_amdgcn_mfma_f32_16x16x32_bf16(bbase1[(16 + j) << 7], ha[j], a1, 0, 0, 0);
          }
        } else {
          if (lane == 0) poll128(cnt0 + ((s + 1) << 9));   // h0hist[s+2] ready (monotone)
          asm volatile("" ::: "memory");
          const unsigned short* asrc = h0hist + (size_t)(s + 2) * BH + bro;  // blocked
          short8 ha[16];
#pragma unroll
          for (int j = 0; j < 16; j++) ha[j] = *(const short8*)(asrc + (j << 11));
#pragma unroll
          for (int j = 0; j < 16; j++) {
            a0 = __builtin_amdgcn_mfma_f32_16x16x32_bf16(bbase0[j << 7], ha[j], a0, 0, 0, 0);
            a1 = __builtin_amdgcn_mfma_f32_16x16x32_bf16(bbase1[j << 7], ha[j], a1, 0, 0, 0);
            ha[j] = *(const short8*)(asrc + ((16 + j) << 11));
          }
#pragma unroll
          for (int j = 0; j < 16; j++) {
            a0 = __builtin_amdgcn_mfma_f32_16x16x32_bf16(bbase0[(16 + j) << 7], ha[j], a0, 0, 0, 0);
            a1 = __builtin_amdgcn_mfma_f32_16x16x32_bf16(bbase1[(16 + j) << 7], ha[j], a1, 0, 0, 0);
          }
        }
        int buf = (s + 1) & 1;
        pbuf[buf][mt][0][lane] = a0;
        pbuf[buf][mt][1][lane] = a1;
      }
    } else {
      // ---- B tight wait: 32 tag words polled concurrently (one per lane) ----
      {
        const unsigned int expv = (unsigned int)(s & 255) * 0x01010101u;
        const int* wp = mytag + ((((s & 3) << 2) + mt) << 9) + ((lane & 31) << 4);
        unsigned int t = (unsigned int)GLD(wp);
        while (t != expv) t = (unsigned int)GLD(wp);
        asm volatile("" ::: "memory");   // no h-load hoisting above the spin
      }
      // ---- recurrent GEMM: h[s] (blocked) x second K-half (rolling-16) ----
      f32x4 acc0 = pbuf[s & 1][mt][0][lane];
      f32x4 acc1 = pbuf[s & 1][mt][1][lane];
      const unsigned short* inB = myhist + (size_t)s * BH + bro;
      short8 ha[16];
#pragma unroll
      for (int j = 0; j < 16; j++) ha[j] = *(const short8*)(inB + (j << 11));
#pragma unroll
      for (int j = 0; j < 16; j++) {
        acc0 = __builtin_amdgcn_mfma_f32_16x16x32_bf16(bbase0[(32 + j) << 7], ha[j], acc0, 0, 0, 0);
        acc1 = __builtin_amdgcn_mfma_f32_16x16x32_bf16(bbase1[(32 + j) << 7], ha[j], acc1, 0, 0, 0);
        ha[j] = *(const short8*)(inB + ((16 + j) << 11));
      }
#pragma unroll
      for (int j = 0; j < 16; j++) {
        acc0 = __builtin_amdgcn_mfma_f32_16x16x32_bf16(bbase0[(48 + j) << 7], ha[j], acc0, 0, 0, 0);
        acc1 = __builtin_amdgcn_mfma_f32_16x16x32_bf16(bbase1[(48 + j) << 7], ha[j], acc1, 0, 0, 0);
      }

      // ---- epilogue: LANE-LOCAL cell update; blocked full-line sc1 h-stores ----
      unsigned short* hbb = myhist + (size_t)(s + 1) * BH + (((g << 6) + m) << 3);
#pragma unroll
      for (int nt2 = 0; nt2 < 2; nt2++) {
        f32x4 acc = nt2 ? acc1 : acc0;
        float ig = fsig(acc[0] + bq[nt2][0]);
        float fg = fsig(acc[1] + bq[nt2][1]);
        float gg = ftanhf(acc[2] + bq[nt2][2]);
        float og = fsig(acc[3] + bq[nt2][3]);
        float cn = ig * gg + fg * creg[nt2];
        float hn = og * ftanhf(cn);
        creg[nt2] = cn;
        GST(hbb + (nt2 << 2) + hi, f2bf(hn));
      }

      // ---- early signal: per-wave drain, then ONE tag byte store ----
      asm volatile("s_waitcnt vmcnt(0)" ::: "memory");
      if (lane == 0) {
        unsigned char* tb = (unsigned char*)(mytag + (((((s + 1) & 3) << 2) + mt) << 9)
                                             + ((g >> 2) << 4)) + (g & 3);
        GST(tb, (unsigned char)((s + 1) & 255));
      }
    }

    // ---- end of step: seal pbuf[(s+1)&1]; L0 publishes monotone cnt0 (L1-A gate) ----
    __syncthreads();
    if (layer == 0 && tid == 0) atomicAdd(cnt0 + (s << 9) + ((g & 7) << 6), 1);

    // ---- final c (once, off the per-step path) ----
    if (!isA && s == TT - 1) {
#pragma unroll
      for (int nt2 = 0; nt2 < 2; nt2++) {
        const int col = nt2 ? col1 : col0;
        out[(size_t)TT * BH + (size_t)(2 + layer) * BH + (m << 10) + col] = creg[nt2];
      }
    }
  }
}

extern "C" void kernel_launch(void* const* d_in, const int* in_sizes, int n_in,
                              void* d_out, int out_size, void* d_ws, size_t ws_size,
                              hipStream_t stream) {
  (void)in_sizes; (void)n_in; (void)out_size; (void)ws_size;
  const float* x    = (const float*)d_in[0];
  const float* h0in = (const float*)d_in[1];
  const float* c0in = (const float*)d_in[2];
  const float* W0   = (const float*)d_in[3];
  const float* b0   = (const float*)d_in[4];
  const float* W1   = (const float*)d_in[5];
  const float* b1   = (const float*)d_in[6];
  float* out = (float*)d_out;

  char* ws = (char*)d_ws;
  const size_t HIST = (size_t)(TT + 1) * BH * sizeof(unsigned short);  // 67,239,936 B
  unsigned short* Xbf    = (unsigned short*)(ws);                      // 64 MB
  unsigned short* W0s    = (unsigned short*)(ws + 67108864);           // 16 MB
  unsigned short* W1s    = (unsigned short*)(ws + 83886080);           // 16 MB
  unsigned short* h0hist = (unsigned short*)(ws + 100663296);          // 64.1 MB
  unsigned short* h1hist = (unsigned short*)(ws + 100663296 + HIST);   // 64.1 MB
  int* tags              = (int*)(ws + 100663296 + 2 * HIST);          // 64 KB (2 layers x 32KB)
  int* cnt0              = tags + 16384;                               // 1 MB

  const size_t ZERO_BYTES = 65536 + (size_t)TT * 512 * sizeof(int);
  hipMemsetAsync(tags, 0, ZERO_BYTES, stream);
  cvt_x_kernel<<<2048, 256, 0, stream>>>(x, Xbf);
  cvt_w_kernel<<<4096, 256, 0, stream>>>(W0, W0s);
  cvt_w_kernel<<<4096, 256, 0, stream>>>(W1, W1s);
  init_state_kernel<<<256, 256, 0, stream>>>(h0in, h0hist, h1hist);

  lstm_persist<<<256, 512, 0, stream>>>(W0s, W1s, b0, b1, Xbf,
                                        h0hist, h1hist, c0in, out, tags, cnt0);

  finalize_kernel<<<2048, 256, 0, stream>>>(h0hist, h1hist, out);
}